// Round 4
// baseline (279.494 us; speedup 1.0000x reference)
//
#include <hip/hip_runtime.h>

typedef __bf16 bf16;
typedef __bf16 bf16x8 __attribute__((ext_vector_type(8)));
typedef __bf16 bf16x4 __attribute__((ext_vector_type(4)));
typedef float floatx4 __attribute__((ext_vector_type(4)));

#define MFMA(a, b, c) __builtin_amdgcn_mfma_f32_16x16x32_bf16((a), (b), (c), 0, 0, 0)

__device__ inline bf16x8 load8(const bf16* p) { return *(const bf16x8*)(p); }
__device__ inline bf16x4 load4(const bf16* p) { return *(const bf16x4*)(p); }
__device__ inline bf16x8 cat44(bf16x4 a, bf16x4 b) {
    return __builtin_shufflevector(a, b, 0, 1, 2, 3, 4, 5, 6, 7);
}

__device__ inline void store_c(bf16* p, float v) { *p = (bf16)v; }
__device__ inline void store_c(float* p, float v) { *p = v; }

// Raw v_exp_f32. Safe: our exponent args are in [-40, 0], far from the f32
// denormal boundary (2^-126), so OCML's denormal-fixup path is dead code here.
__device__ inline float fast_exp2(float x) {
#if __has_builtin(__builtin_amdgcn_exp2f)
    return __builtin_amdgcn_exp2f(x);
#else
    float r;
    asm("v_exp_f32 %0, %1" : "=v"(r) : "v"(x));
    return r;
#endif
}

__device__ inline float fast_rcp(float x) {
#if __has_builtin(__builtin_amdgcn_rcpf)
    return __builtin_amdgcn_rcpf(x);
#else
    float r;
    asm("v_rcp_f32 %0, %1" : "=v"(r) : "v"(x));
    return r;
#endif
}

// Async global->LDS, 16B/lane; dest = wave-uniform base + lane*16.
__device__ inline void gload_lds(const bf16* g, bf16* l) {
    __builtin_amdgcn_global_load_lds(
        (const __attribute__((address_space(1))) void*)(g),
        (__attribute__((address_space(3))) void*)(l), 16, 0, 0);
}

// ---------------- fp32 -> bf16 bulk convert (7 tensors, one dispatch) ------
struct CvtArgs {
    const float* src[7];
    bf16* dst[7];
    int n[7];
};
__global__ __launch_bounds__(256) void cvt_bf16(CvtArgs a) {
    const int t = blockIdx.y;
    const int i = (blockIdx.x * 256 + threadIdx.x) * 8;
    if (i >= a.n[t]) return;
    const float4 u = *(const float4*)(a.src[t] + i);
    const float4 v = *(const float4*)(a.src[t] + i + 4);
    bf16x8 r;
    r[0] = (bf16)u.x; r[1] = (bf16)u.y; r[2] = (bf16)u.z; r[3] = (bf16)u.w;
    r[4] = (bf16)v.x; r[5] = (bf16)v.y; r[6] = (bf16)v.z; r[7] = (bf16)v.w;
    *(bf16x8*)(a.dst[t] + i) = r;
}

// ---------------- m97-style LDS GEMM (validated round 8) -------------------
template <typename TC>
__device__ inline void gemm_core(const bf16* __restrict__ A, const bf16* __restrict__ W,
                                 const float* __restrict__ bias, TC* __restrict__ C,
                                 bool TR) {
    __shared__ bf16 As[2][128][32];
    __shared__ bf16 Bs[2][128][32];

    const int tid = threadIdx.x;
    const int wv = tid >> 6, lane = tid & 63;
    const int quad = lane >> 4, lo = lane & 15;
    const int wm = wv >> 1, wn = wv & 1;
    const int Ar0 = blockIdx.y * 128, Br0 = blockIdx.x * 128;

    const int srow = lane >> 2, sseg = (lane & 3) ^ (srow & 3);
    const bf16* Ag = A + (size_t)(Ar0 + srow) * 1024 + sseg * 8;
    const bf16* Bg = W + (size_t)(Br0 + srow) * 1024 + sseg * 8;

    auto stage = [&](int buf, int k0) {
#pragma unroll
        for (int c = 2 * wv; c < 2 * wv + 2; c++) {
            gload_lds(Ag + (size_t)c * 16 * 1024 + k0, &As[buf][c * 16][0]);
            gload_lds(Bg + (size_t)c * 16 * 1024 + k0, &Bs[buf][c * 16][0]);
        }
    };

    floatx4 acc[4][4] = {};
    const int rs = (quad ^ (lo & 3)) * 8;

    stage(0, 0);
    for (int k0 = 0; k0 < 1024; k0 += 32) {
        const int buf = (k0 >> 5) & 1;
        __syncthreads();
        if (k0 + 32 < 1024) stage(buf ^ 1, k0 + 32);

        bf16x8 a[4], b[4];
#pragma unroll
        for (int i = 0; i < 4; i++) a[i] = load8(&As[buf][wm * 64 + i * 16 + lo][rs]);
#pragma unroll
        for (int j = 0; j < 4; j++) b[j] = load8(&Bs[buf][wn * 64 + j * 16 + lo][rs]);
#pragma unroll
        for (int i = 0; i < 4; i++)
#pragma unroll
            for (int j = 0; j < 4; j++) acc[i][j] = MFMA(a[i], b[j], acc[i][j]);
    }

#pragma unroll
    for (int i = 0; i < 4; i++) {
#pragma unroll
        for (int j = 0; j < 4; j++) {
#pragma unroll
            for (int r = 0; r < 4; r++) {
                const int m = Ar0 + wm * 64 + i * 16 + quad * 4 + r;
                const int n = Br0 + wn * 64 + j * 16 + lo;
                const float v = acc[i][j][r] + bias[n];
                if (!TR) {
                    store_c(C + (size_t)m * 1024 + n, v);
                } else {
                    store_c(C + (size_t)(n >> 6) * (64 * 4096) + (size_t)(n & 63) * 4096 + m, v);
                }
            }
        }
    }
}

__global__ __launch_bounds__(256) void gemm_qkv(
    const bf16* __restrict__ qb, const bf16* __restrict__ kb, const bf16* __restrict__ vb,
    const bf16* __restrict__ Wq, const bf16* __restrict__ Wk, const bf16* __restrict__ Wv,
    const float* __restrict__ bq, const float* __restrict__ bk, const float* __restrict__ bv,
    bf16* __restrict__ Q, bf16* __restrict__ Kp, bf16* __restrict__ Vt) {
    if (blockIdx.z == 0)
        gemm_core<bf16>(qb, Wq, bq, Q, false);
    else if (blockIdx.z == 1)
        gemm_core<bf16>(kb, Wk, bk, Kp, false);
    else
        gemm_core<bf16>(vb, Wv, bv, Vt, true);  // Vt[h][d][s]
}

__global__ __launch_bounds__(256) void gemm_o(const bf16* __restrict__ O,
                                              const bf16* __restrict__ Wo,
                                              const float* __restrict__ bo,
                                              float* __restrict__ out) {
    gemm_core<float>(O, Wo, bo, out, false);
}

// ---------------- flash v9: in-reg P + T15 double-pipeline -----------------
// r3 theory: v6/v7/v8 all show VALU~50 / MFMA~31 / LDS~50, none saturated ->
// the limiter is the serial per-iter chain S-MFMA -> exp -> P -> PV-MFMA with
// only 2 waves/SIMD to hide it. T15 (att[2], +7-11% in m214v36): keep the
// previous tile's P in registers (aPrev, in-reg P layout from v7) and issue
// PV[i-1] immediately after S[i]'s MFMAs -- 36 back-to-back independent
// MFMAs, with exp[i] VALU sliding under their shadow. V needs 3 LDS buffers
// (stage target (i+1)%3 vs PV read (i-1)%3 differ by 2 mod 3: always
// distinct); K keeps 2. Hard constraint from v8's failure: 32 q-rows/wave
// minimum (K/V fragment reads amortize over q-rows).
__global__ __launch_bounds__(256) void flash_attn9(const bf16* __restrict__ Q,
                                                   const bf16* __restrict__ Kmat,
                                                   const bf16* __restrict__ Vt,
                                                   bf16* __restrict__ O) {
    __shared__ bf16 Ks[2][64][64];
    __shared__ bf16 Vs[3][64][64];

    const int tid = threadIdx.x;
    const int wv = tid >> 6;
    const int lane = tid & 63;
    const int quad = lane >> 4, lo = lane & 15;
    const int h = blockIdx.x;
    const int qb = blockIdx.y;
    const int DM = 1024;
    const int q0 = qb * 128 + wv * 32;

    bf16x8 aQ[2][2];
#pragma unroll
    for (int qs = 0; qs < 2; qs++) {
        const bf16* qp = Q + (size_t)(q0 + qs * 16 + lo) * DM + h * 64 + quad * 8;
        aQ[qs][0] = load8(qp);
        aQ[qs][1] = load8(qp + 32);
    }

    bf16x8 bOnes;
#pragma unroll
    for (int i = 0; i < 8; i++) bOnes[i] = (bf16)1.0f;

    floatx4 Oacc[2][4] = {};
    floatx4 Lacc[2] = {};

    const int srow = lane >> 3, sseg = (lane & 7) ^ srow;
    const bf16* Kg = Kmat + (size_t)srow * DM + h * 64 + sseg * 8;
    const bf16* Vg = Vt + (size_t)h * 64 * 4096 + (size_t)srow * 4096 + sseg * 8;

    auto stageK = [&](int kb, int kb2) {
#pragma unroll
        for (int c = 2 * wv; c < 2 * wv + 2; c++)
            gload_lds(Kg + (size_t)(kb2 + c * 8) * DM, &Ks[kb][c * 8][0]);
    };
    auto stageV = [&](int vb, int kb2) {
#pragma unroll
        for (int c = 2 * wv; c < 2 * wv + 2; c++)
            gload_lds(Vg + (size_t)(c * 8) * 4096 + kb2, &Vs[vb][c * 8][0]);
    };

    const float C_SCALE = 0.18033688011112043f;  // 0.125 * log2(e)
    const float C_BIAS = 23.083120654223415f;    // 16 * log2(e)
    const int sw = lo & 7;
    const int vo = quad >> 1;        // V gather: logical-seg contribution
    const int vlo = (quad & 1) * 4;  // V gather: element offset in segment

    bf16x8 aPrev[2][2];  // packed P of the previous tile, [qs][kk]

    // PV for one tile from registers (aPrev) + Vs[vb].
    auto pv = [&](int vb) {
#pragma unroll
        for (int kk = 0; kk < 2; kk++) {
            Lacc[0] = MFMA(aPrev[0][kk], bOnes, Lacc[0]);
            Lacc[1] = MFMA(aPrev[1][kk], bOnes, Lacc[1]);
#pragma unroll
            for (int nt = 0; nt < 4; nt++) {
                const bf16* vrow = &Vs[vb][nt * 16 + lo][0];
                const bf16x4 v0 = load4(vrow + (((kk * 4 + vo) ^ sw) << 3) + vlo);
                const bf16x4 v1 = load4(vrow + (((kk * 4 + 2 + vo) ^ sw) << 3) + vlo);
                const bf16x8 bV = cat44(v0, v1);
                Oacc[0][nt] = MFMA(aPrev[0][kk], bV, Oacc[0][nt]);
                Oacc[1][nt] = MFMA(aPrev[1][kk], bV, Oacc[1][nt]);
            }
        }
    };

    stageK(0, 0);
    stageV(0, 0);
    for (int i = 0; i < 64; i++) {
        const int kbuf = i & 1;
        __syncthreads();
        if (i + 1 < 64) {
            stageK(kbuf ^ 1, (i + 1) * 64);
            stageV((i + 1) % 3, (i + 1) * 64);
        }

        // ---- S^T tile i: rows=keys (t*16+quad*4+r), cols=q (lo) ----
        floatx4 st[2][4];
#pragma unroll
        for (int t = 0; t < 4; t++) {
            const bf16* krow = &Ks[kbuf][t * 16 + lo][0];
            const bf16x8 aK0 = load8(krow + ((quad ^ sw) * 8));
            const bf16x8 aK1 = load8(krow + (((quad + 4) ^ sw) * 8));
#pragma unroll
            for (int qs = 0; qs < 2; qs++) {
                floatx4 z = {};
                z = MFMA(aK0, aQ[qs][0], z);
                st[qs][t] = MFMA(aK1, aQ[qs][1], z);
            }
        }

        // ---- PV for tile i-1 (registers + Vs[(i-1)%3]) ----
        if (i > 0) pv((i + 2) % 3);

        // ---- exp + pack tile i into aPrev ----
        bf16x4 pp[2][4];
#pragma unroll
        for (int qs = 0; qs < 2; qs++)
#pragma unroll
            for (int t = 0; t < 4; t++)
#pragma unroll
                for (int r = 0; r < 4; r++)
                    pp[qs][t][r] = (bf16)fast_exp2(fmaf(st[qs][t][r], C_SCALE, -C_BIAS));
#pragma unroll
        for (int qs = 0; qs < 2; qs++)
#pragma unroll
            for (int kk = 0; kk < 2; kk++)
                aPrev[qs][kk] = cat44(pp[qs][2 * kk], pp[qs][2 * kk + 1]);
    }
    // ---- final PV for tile 63 (Vs[63%3], staged at i=62, sync'd at i=63) ----
    pv(63 % 3);

    // ---- epilogue: l is per-(q-row) in Lacc C-layout; divide, store ----
#pragma unroll
    for (int qs = 0; qs < 2; qs++)
#pragma unroll
        for (int r = 0; r < 4; r++) {
            const float inv = fast_rcp(Lacc[qs][r]);
#pragma unroll
            for (int nt = 0; nt < 4; nt++) {
                O[(size_t)(q0 + qs * 16 + quad * 4 + r) * DM + h * 64 + nt * 16 + lo] =
                    (bf16)(Oacc[qs][nt][r] * inv);
            }
        }
}

extern "C" void kernel_launch(void* const* d_in, const int* in_sizes, int n_in,
                              void* d_out, int out_size, void* d_ws, size_t ws_size,
                              hipStream_t stream) {
    const float* query = (const float*)d_in[0];
    const float* key_i = (const float*)d_in[1];
    const float* value = (const float*)d_in[2];
    const float* Wq = (const float*)d_in[3];
    const float* bq = (const float*)d_in[4];
    const float* Wk = (const float*)d_in[5];
    const float* bk = (const float*)d_in[6];
    const float* Wv = (const float*)d_in[7];
    const float* bv = (const float*)d_in[8];
    const float* Wo = (const float*)d_in[9];
    const float* bo = (const float*)d_in[10];

    bf16* ws = (bf16*)d_ws;
    const size_t SZ = (size_t)4096 * 1024;  // 4M elems
    const size_t WZ = (size_t)1024 * 1024;  // 1M elems
    // 56 MB layout; O aliases qb (dead after gemm_qkv).
    bf16* qb = ws;                  // 4M
    bf16* kb = ws + SZ;             // 4M
    bf16* vb = ws + 2 * SZ;         // 4M
    bf16* Wqb = ws + 3 * SZ;        // 1M
    bf16* Wkb = ws + 3 * SZ + WZ;   // 1M
    bf16* Wvb = ws + 3 * SZ + 2 * WZ;
    bf16* Wob = ws + 3 * SZ + 3 * WZ;
    bf16* Q = ws + 3 * SZ + 4 * WZ;  // 4M
    bf16* K = Q + SZ;                // 4M
    bf16* Vt = Q + 2 * SZ;           // 4M
    bf16* O = qb;                    // alias

    CvtArgs ca;
    const int SZi = 4096 * 1024, WZi = 1024 * 1024;
    ca.src[0] = query; ca.dst[0] = qb;  ca.n[0] = SZi;
    ca.src[1] = key_i; ca.dst[1] = kb;  ca.n[1] = SZi;
    ca.src[2] = value; ca.dst[2] = vb;  ca.n[2] = SZi;
    ca.src[3] = Wq;    ca.dst[3] = Wqb; ca.n[3] = WZi;
    ca.src[4] = Wk;    ca.dst[4] = Wkb; ca.n[4] = WZi;
    ca.src[5] = Wv;    ca.dst[5] = Wvb; ca.n[5] = WZi;
    ca.src[6] = Wo;    ca.dst[6] = Wob; ca.n[6] = WZi;
    cvt_bf16<<<dim3(2048, 7), 256, 0, stream>>>(ca);

    gemm_qkv<<<dim3(8, 32, 3), 256, 0, stream>>>(qb, kb, vb, Wqb, Wkb, Wvb,
                                                 bq, bk, bv, Q, K, Vt);
    flash_attn9<<<dim3(16, 32), 256, 0, stream>>>(Q, K, Vt, O);
    gemm_o<<<dim3(8, 32), 256, 0, stream>>>(O, Wob, bo, (float*)d_out);
}

// Round 5
// 275.282 us; speedup vs baseline: 1.0153x; 1.0153x over previous
//
#include <hip/hip_runtime.h>

typedef __bf16 bf16;
typedef __bf16 bf16x8 __attribute__((ext_vector_type(8)));
typedef __bf16 bf16x4 __attribute__((ext_vector_type(4)));
typedef float floatx4 __attribute__((ext_vector_type(4)));

#define MFMA(a, b, c) __builtin_amdgcn_mfma_f32_16x16x32_bf16((a), (b), (c), 0, 0, 0)

__device__ inline bf16x8 load8(const bf16* p) { return *(const bf16x8*)(p); }

__device__ inline void store_c(bf16* p, float v) { *p = (bf16)v; }
__device__ inline void store_c(float* p, float v) { *p = v; }

// Raw v_exp_f32. Safe: our exponent args are in [-40, 0], far from the f32
// denormal boundary (2^-126), so OCML's denormal-fixup path is dead code here.
__device__ inline float fast_exp2(float x) {
#if __has_builtin(__builtin_amdgcn_exp2f)
    return __builtin_amdgcn_exp2f(x);
#else
    float r;
    asm("v_exp_f32 %0, %1" : "=v"(r) : "v"(x));
    return r;
#endif
}

__device__ inline float fast_rcp(float x) {
#if __has_builtin(__builtin_amdgcn_rcpf)
    return __builtin_amdgcn_rcpf(x);
#else
    float r;
    asm("v_rcp_f32 %0, %1" : "=v"(r) : "v"(x));
    return r;
#endif
}

// Async global->LDS, 16B/lane; dest = wave-uniform base + lane*16.
__device__ inline void gload_lds(const bf16* g, bf16* l) {
    __builtin_amdgcn_global_load_lds(
        (const __attribute__((address_space(1))) void*)(g),
        (__attribute__((address_space(3))) void*)(l), 16, 0, 0);
}

// ---------------- fp32 -> bf16 bulk convert (7 tensors, one dispatch) ------
struct CvtArgs {
    const float* src[7];
    bf16* dst[7];
    int n[7];
};
__global__ __launch_bounds__(256) void cvt_bf16(CvtArgs a) {
    const int t = blockIdx.y;
    const int i = (blockIdx.x * 256 + threadIdx.x) * 8;
    if (i >= a.n[t]) return;
    const float4 u = *(const float4*)(a.src[t] + i);
    const float4 v = *(const float4*)(a.src[t] + i + 4);
    bf16x8 r;
    r[0] = (bf16)u.x; r[1] = (bf16)u.y; r[2] = (bf16)u.z; r[3] = (bf16)u.w;
    r[4] = (bf16)v.x; r[5] = (bf16)v.y; r[6] = (bf16)v.z; r[7] = (bf16)v.w;
    *(bf16x8*)(a.dst[t] + i) = r;
}

// ---------------- m97-style LDS GEMM (validated round 8) -------------------
template <typename TC>
__device__ inline void gemm_core(const bf16* __restrict__ A, const bf16* __restrict__ W,
                                 const float* __restrict__ bias, TC* __restrict__ C,
                                 bool TR) {
    __shared__ bf16 As[2][128][32];
    __shared__ bf16 Bs[2][128][32];

    const int tid = threadIdx.x;
    const int wv = tid >> 6, lane = tid & 63;
    const int quad = lane >> 4, lo = lane & 15;
    const int wm = wv >> 1, wn = wv & 1;
    const int Ar0 = blockIdx.y * 128, Br0 = blockIdx.x * 128;

    const int srow = lane >> 2, sseg = (lane & 3) ^ (srow & 3);
    const bf16* Ag = A + (size_t)(Ar0 + srow) * 1024 + sseg * 8;
    const bf16* Bg = W + (size_t)(Br0 + srow) * 1024 + sseg * 8;

    auto stage = [&](int buf, int k0) {
#pragma unroll
        for (int c = 2 * wv; c < 2 * wv + 2; c++) {
            gload_lds(Ag + (size_t)c * 16 * 1024 + k0, &As[buf][c * 16][0]);
            gload_lds(Bg + (size_t)c * 16 * 1024 + k0, &Bs[buf][c * 16][0]);
        }
    };

    floatx4 acc[4][4] = {};
    const int rs = (quad ^ (lo & 3)) * 8;

    stage(0, 0);
    for (int k0 = 0; k0 < 1024; k0 += 32) {
        const int buf = (k0 >> 5) & 1;
        __syncthreads();
        if (k0 + 32 < 1024) stage(buf ^ 1, k0 + 32);

        bf16x8 a[4], b[4];
#pragma unroll
        for (int i = 0; i < 4; i++) a[i] = load8(&As[buf][wm * 64 + i * 16 + lo][rs]);
#pragma unroll
        for (int j = 0; j < 4; j++) b[j] = load8(&Bs[buf][wn * 64 + j * 16 + lo][rs]);
#pragma unroll
        for (int i = 0; i < 4; i++)
#pragma unroll
            for (int j = 0; j < 4; j++) acc[i][j] = MFMA(a[i], b[j], acc[i][j]);
    }

#pragma unroll
    for (int i = 0; i < 4; i++) {
#pragma unroll
        for (int j = 0; j < 4; j++) {
#pragma unroll
            for (int r = 0; r < 4; r++) {
                const int m = Ar0 + wm * 64 + i * 16 + quad * 4 + r;
                const int n = Br0 + wn * 64 + j * 16 + lo;
                const float v = acc[i][j][r] + bias[n];
                if (!TR) {
                    store_c(C + (size_t)m * 1024 + n, v);
                } else {
                    store_c(C + (size_t)(n >> 6) * (64 * 4096) + (size_t)(n & 63) * 4096 + m, v);
                }
            }
        }
    }
}

__global__ __launch_bounds__(256) void gemm_qkv(
    const bf16* __restrict__ qb, const bf16* __restrict__ kb, const bf16* __restrict__ vb,
    const bf16* __restrict__ Wq, const bf16* __restrict__ Wk, const bf16* __restrict__ Wv,
    const float* __restrict__ bq, const float* __restrict__ bk, const float* __restrict__ bv,
    bf16* __restrict__ Q, bf16* __restrict__ Kp, bf16* __restrict__ Vt) {
    if (blockIdx.z == 0)
        gemm_core<bf16>(qb, Wq, bq, Q, false);
    else if (blockIdx.z == 1)
        gemm_core<bf16>(kb, Wk, bk, Kp, false);
    else
        gemm_core<bf16>(vb, Wv, bv, Vt, true);  // Vt[h][d][s]
}

__global__ __launch_bounds__(256) void gemm_o(const bf16* __restrict__ O,
                                              const bf16* __restrict__ Wo,
                                              const float* __restrict__ bo,
                                              float* __restrict__ out) {
    gemm_core<float>(O, Wo, bo, out, false);
}

// ---------------- flash v10: v6 body + split-K(2) + setprio ----------------
// r4 theory: v7/v8/v9 all failed -> v6's structure is a compiler-friendly
// local optimum; the limiter is wave count (Occ 20% = 2 waves/SIMD, no pipe
// >50%). Grid is the cap (512 blocks = 2/CU). Fixed-bias softmax (no running
// max) makes key-split partials combine LINEARLY: O = (P0+P1)/(l0+l1). So:
// grid (16,32,2), each block runs the byte-identical v6 loop over 2048 keys,
// writes f32 unnormalized O-partial + l-partial; tiny combine kernel divides.
// LDS 50KB -> 3 blocks/CU -> 12 waves/CU (+50% slots). T5 setprio around
// MFMA clusters (catalog: attn +4-7%, more to arbitrate at 3 waves/SIMD).
__global__ __launch_bounds__(256) void flash_attn10(const bf16* __restrict__ Q,
                                                    const bf16* __restrict__ Kmat,
                                                    const bf16* __restrict__ Vt,
                                                    float* __restrict__ Pp,
                                                    float* __restrict__ lb) {
    __shared__ bf16 Ks[2][64][64];
    __shared__ bf16 Vs[2][64][64];
    __shared__ __align__(16) bf16 Ps[4][2][16][72];

    const int tid = threadIdx.x;
    const int wv = tid >> 6;
    const int lane = tid & 63;
    const int quad = lane >> 4, lo = lane & 15;
    const int h = blockIdx.x;
    const int qb = blockIdx.y;
    const int z = blockIdx.z;
    const int kv0 = z * 2048;
    const int DM = 1024;
    const int q0 = qb * 128 + wv * 32;

    float* myP = Pp + (size_t)z * 4096 * 1024;
    float* myl = lb + z * 65536 + h * 4096;

    bf16x8 aQ[2][2];
#pragma unroll
    for (int qs = 0; qs < 2; qs++) {
        const bf16* qp = Q + (size_t)(q0 + qs * 16 + lo) * DM + h * 64 + quad * 8;
        aQ[qs][0] = load8(qp);
        aQ[qs][1] = load8(qp + 32);
    }

    bf16x8 bOnes;
#pragma unroll
    for (int i = 0; i < 8; i++) bOnes[i] = (bf16)1.0f;

    floatx4 Oacc[2][4] = {};
    floatx4 Lacc[2] = {};

    const int srow = lane >> 3, sseg = (lane & 7) ^ srow;
    const bf16* Kg = Kmat + (size_t)srow * DM + h * 64 + sseg * 8;
    const bf16* Vg = Vt + (size_t)h * 64 * 4096 + (size_t)srow * 4096 + sseg * 8;

    auto stage = [&](int buf, int kb2) {
#pragma unroll
        for (int c = 2 * wv; c < 2 * wv + 2; c++) {
            gload_lds(Kg + (size_t)(kb2 + c * 8) * DM, &Ks[buf][c * 8][0]);
            gload_lds(Vg + (size_t)(c * 8) * 4096 + kb2, &Vs[buf][c * 8][0]);
        }
    };

    const float C_SCALE = 0.18033688011112043f;  // 0.125 * log2(e)
    const float C_BIAS = 23.083120654223415f;    // 16 * log2(e)
    const int sw = lo & 7;

    stage(0, kv0);
    for (int kb2 = kv0; kb2 < kv0 + 2048; kb2 += 64) {
        const int buf = (kb2 >> 6) & 1;
        __syncthreads();
        if (kb2 + 64 < kv0 + 2048) stage(buf ^ 1, kb2 + 64);

        // ---- S^T tile: rows=keys (t*16+quad*4+r), cols=q (lo) ----
        floatx4 st[2][4];
        __builtin_amdgcn_s_setprio(1);
#pragma unroll
        for (int t = 0; t < 4; t++) {
            const bf16* krow = &Ks[buf][t * 16 + lo][0];
            const bf16x8 aK0 = load8(krow + ((quad ^ sw) * 8));
            const bf16x8 aK1 = load8(krow + (((quad + 4) ^ sw) * 8));
#pragma unroll
            for (int qs = 0; qs < 2; qs++) {
                floatx4 z2 = {};
                z2 = MFMA(aK0, aQ[qs][0], z2);
                st[qs][t] = MFMA(aK1, aQ[qs][1], z2);
            }
        }
        __builtin_amdgcn_s_setprio(0);

        // ---- p = 2^(s*scale - bias); 4 consecutive keys/lane -> b64 write ----
#pragma unroll
        for (int qs = 0; qs < 2; qs++)
#pragma unroll
            for (int t = 0; t < 4; t++) {
                bf16x4 pp;
#pragma unroll
                for (int r = 0; r < 4; r++)
                    pp[r] = (bf16)fast_exp2(fmaf(st[qs][t][r], C_SCALE, -C_BIAS));
                *(bf16x4*)(&Ps[wv][qs][lo][t * 16 + quad * 4]) = pp;
            }

        // ---- PV + l-accum: O[q][d] += P V^T; l[q] += P*ones ----
        __builtin_amdgcn_s_setprio(1);
#pragma unroll
        for (int kk = 0; kk < 2; kk++) {
            bf16x8 aP[2];
            aP[0] = load8(&Ps[wv][0][lo][kk * 32 + quad * 8]);
            aP[1] = load8(&Ps[wv][1][lo][kk * 32 + quad * 8]);
            Lacc[0] = MFMA(aP[0], bOnes, Lacc[0]);
            Lacc[1] = MFMA(aP[1], bOnes, Lacc[1]);
#pragma unroll
            for (int nt = 0; nt < 4; nt++) {
                const bf16x8 bV = load8(&Vs[buf][nt * 16 + lo][(((kk * 4 + quad) ^ sw) * 8)]);
                Oacc[0][nt] = MFMA(aP[0], bV, Oacc[0][nt]);
                Oacc[1][nt] = MFMA(aP[1], bV, Oacc[1][nt]);
            }
        }
        __builtin_amdgcn_s_setprio(0);
    }

    // ---- epilogue: write unnormalized f32 partial + l-partial ----
#pragma unroll
    for (int qs = 0; qs < 2; qs++)
#pragma unroll
        for (int r = 0; r < 4; r++) {
            const int row = q0 + qs * 16 + quad * 4 + r;
            if (lo == 0) myl[row] = Lacc[qs][r];
#pragma unroll
            for (int nt = 0; nt < 4; nt++) {
                myP[(size_t)row * DM + h * 64 + nt * 16 + lo] = Oacc[qs][nt][r];
            }
        }
}

// ---------------- combine: O = (P0+P1)/(l0+l1), f32 -> bf16 ----------------
__global__ __launch_bounds__(256) void combine_o(const float* __restrict__ P,
                                                 const float* __restrict__ lb,
                                                 bf16* __restrict__ Ob) {
    const size_t i = (size_t)(blockIdx.x * 256 + threadIdx.x) * 8;
    const int row = (int)(i >> 10), col = (int)(i & 1023), h = col >> 6;
    const float l = lb[h * 4096 + row] + lb[65536 + h * 4096 + row];
    const float inv = fast_rcp(l);
    const float4 a0 = *(const float4*)(P + i);
    const float4 a1 = *(const float4*)(P + i + 4);
    const float4 b0 = *(const float4*)(P + 4194304 + i);
    const float4 b1 = *(const float4*)(P + 4194304 + i + 4);
    bf16x8 r;
    r[0] = (bf16)((a0.x + b0.x) * inv);
    r[1] = (bf16)((a0.y + b0.y) * inv);
    r[2] = (bf16)((a0.z + b0.z) * inv);
    r[3] = (bf16)((a0.w + b0.w) * inv);
    r[4] = (bf16)((a1.x + b1.x) * inv);
    r[5] = (bf16)((a1.y + b1.y) * inv);
    r[6] = (bf16)((a1.z + b1.z) * inv);
    r[7] = (bf16)((a1.w + b1.w) * inv);
    *(bf16x8*)(Ob + i) = r;
}

extern "C" void kernel_launch(void* const* d_in, const int* in_sizes, int n_in,
                              void* d_out, int out_size, void* d_ws, size_t ws_size,
                              hipStream_t stream) {
    const float* query = (const float*)d_in[0];
    const float* key_i = (const float*)d_in[1];
    const float* value = (const float*)d_in[2];
    const float* Wq = (const float*)d_in[3];
    const float* bq = (const float*)d_in[4];
    const float* Wk = (const float*)d_in[5];
    const float* bk = (const float*)d_in[6];
    const float* Wv = (const float*)d_in[7];
    const float* bv = (const float*)d_in[8];
    const float* Wo = (const float*)d_in[9];
    const float* bo = (const float*)d_in[10];

    bf16* ws = (bf16*)d_ws;
    const size_t SZ = (size_t)4096 * 1024;  // 4M elems (8MB bf16)
    const size_t WZ = (size_t)1024 * 1024;  // 1M elems (2MB bf16)
    // 58.5MB layout. Phase 1 (cvt+gemm_qkv): qb..Wob live.
    // Phase 2 (flash): Q,K,Vt live; P0=[0,16MB) over qb+kb; P1=[16,32MB) over
    // vb+Wqb+Wkb+Wvb+pad (all dead). Phase 3: combine writes O into Q slot
    // (dead); gemm_o reads it. Wob lives at 56MB, l-partials at 58MB.
    bf16* qb = ws;                       // 8MB
    bf16* kb = ws + SZ;                  // 8MB
    bf16* vb = ws + 2 * SZ;              // 8MB
    bf16* Wqb = ws + 3 * SZ;             // 2MB
    bf16* Wkb = ws + 3 * SZ + WZ;        // 2MB
    bf16* Wvb = ws + 3 * SZ + 2 * WZ;    // 2MB
    // 2MB pad at ws + 3*SZ + 3*WZ (tail of P1)
    bf16* Q = ws + 3 * SZ + 4 * WZ;      // 8MB @32MB; O bf16 after flash
    bf16* K = Q + SZ;                    // 8MB @40MB
    bf16* Vt = Q + 2 * SZ;               // 8MB @48MB
    bf16* Wob = ws + 6 * SZ + 4 * WZ;    // 2MB @56MB
    float* lbuf = (float*)(ws + 6 * SZ + 5 * WZ);  // 512KB @58MB
    float* Pp = (float*)ws;              // P0 @0, P1 @16MB (contiguous f32)
    bf16* O = Q;                         // combine output aliases Q (dead)

    CvtArgs ca;
    const int SZi = 4096 * 1024, WZi = 1024 * 1024;
    ca.src[0] = query; ca.dst[0] = qb;  ca.n[0] = SZi;
    ca.src[1] = key_i; ca.dst[1] = kb;  ca.n[1] = SZi;
    ca.src[2] = value; ca.dst[2] = vb;  ca.n[2] = SZi;
    ca.src[3] = Wq;    ca.dst[3] = Wqb; ca.n[3] = WZi;
    ca.src[4] = Wk;    ca.dst[4] = Wkb; ca.n[4] = WZi;
    ca.src[5] = Wv;    ca.dst[5] = Wvb; ca.n[5] = WZi;
    ca.src[6] = Wo;    ca.dst[6] = Wob; ca.n[6] = WZi;
    cvt_bf16<<<dim3(2048, 7), 256, 0, stream>>>(ca);

    gemm_qkv<<<dim3(8, 32, 3), 256, 0, stream>>>(qb, kb, vb, Wqb, Wkb, Wvb,
                                                 bq, bk, bv, Q, K, Vt);
    flash_attn10<<<dim3(16, 32, 2), 256, 0, stream>>>(Q, K, Vt, Pp, lbuf);
    combine_o<<<2048, 256, 0, stream>>>(Pp, lbuf, O);
    gemm_o<<<dim3(8, 32), 256, 0, stream>>>(O, Wob, bo, (float*)d_out);
}

// Round 6
// 273.061 us; speedup vs baseline: 1.0236x; 1.0081x over previous
//
#include <hip/hip_runtime.h>

typedef __bf16 bf16;
typedef __bf16 bf16x8 __attribute__((ext_vector_type(8)));
typedef __bf16 bf16x4 __attribute__((ext_vector_type(4)));
typedef float floatx4 __attribute__((ext_vector_type(4)));

#define MFMA(a, b, c) __builtin_amdgcn_mfma_f32_16x16x32_bf16((a), (b), (c), 0, 0, 0)

__device__ inline bf16x8 load8(const bf16* p) { return *(const bf16x8*)(p); }
__device__ inline bf16x4 load4(const bf16* p) { return *(const bf16x4*)(p); }
__device__ inline bf16x8 cat44(bf16x4 a, bf16x4 b) {
    return __builtin_shufflevector(a, b, 0, 1, 2, 3, 4, 5, 6, 7);
}

__device__ inline void store_c(bf16* p, float v) { *p = (bf16)v; }
__device__ inline void store_c(float* p, float v) { *p = v; }

// Raw v_exp_f32. Safe: our exponent args are in [-40, 0], far from the f32
// denormal boundary (2^-126), so OCML's denormal-fixup path is dead code here.
__device__ inline float fast_exp2(float x) {
#if __has_builtin(__builtin_amdgcn_exp2f)
    return __builtin_amdgcn_exp2f(x);
#else
    float r;
    asm("v_exp_f32 %0, %1" : "=v"(r) : "v"(x));
    return r;
#endif
}

__device__ inline float fast_rcp(float x) {
#if __has_builtin(__builtin_amdgcn_rcpf)
    return __builtin_amdgcn_rcpf(x);
#else
    float r;
    asm("v_rcp_f32 %0, %1" : "=v"(r) : "v"(x));
    return r;
#endif
}

// Async global->LDS, 16B/lane; dest = wave-uniform base + lane*16.
__device__ inline void gload_lds(const bf16* g, bf16* l) {
    __builtin_amdgcn_global_load_lds(
        (const __attribute__((address_space(1))) void*)(g),
        (__attribute__((address_space(3))) void*)(l), 16, 0, 0);
}

// ---------------- fp32 -> bf16 bulk convert (7 tensors, one dispatch) ------
struct CvtArgs {
    const float* src[7];
    bf16* dst[7];
    int n[7];
};
__global__ __launch_bounds__(256) void cvt_bf16(CvtArgs a) {
    const int t = blockIdx.y;
    const int i = (blockIdx.x * 256 + threadIdx.x) * 8;
    if (i >= a.n[t]) return;
    const float4 u = *(const float4*)(a.src[t] + i);
    const float4 v = *(const float4*)(a.src[t] + i + 4);
    bf16x8 r;
    r[0] = (bf16)u.x; r[1] = (bf16)u.y; r[2] = (bf16)u.z; r[3] = (bf16)u.w;
    r[4] = (bf16)v.x; r[5] = (bf16)v.y; r[6] = (bf16)v.z; r[7] = (bf16)v.w;
    *(bf16x8*)(a.dst[t] + i) = r;
}

// ---------------- m97-style LDS GEMM (validated round 8) -------------------
template <typename TC>
__device__ inline void gemm_core(const bf16* __restrict__ A, const bf16* __restrict__ W,
                                 const float* __restrict__ bias, TC* __restrict__ C,
                                 bool TR) {
    __shared__ bf16 As[2][128][32];
    __shared__ bf16 Bs[2][128][32];

    const int tid = threadIdx.x;
    const int wv = tid >> 6, lane = tid & 63;
    const int quad = lane >> 4, lo = lane & 15;
    const int wm = wv >> 1, wn = wv & 1;
    const int Ar0 = blockIdx.y * 128, Br0 = blockIdx.x * 128;

    const int srow = lane >> 2, sseg = (lane & 3) ^ (srow & 3);
    const bf16* Ag = A + (size_t)(Ar0 + srow) * 1024 + sseg * 8;
    const bf16* Bg = W + (size_t)(Br0 + srow) * 1024 + sseg * 8;

    auto stage = [&](int buf, int k0) {
#pragma unroll
        for (int c = 2 * wv; c < 2 * wv + 2; c++) {
            gload_lds(Ag + (size_t)c * 16 * 1024 + k0, &As[buf][c * 16][0]);
            gload_lds(Bg + (size_t)c * 16 * 1024 + k0, &Bs[buf][c * 16][0]);
        }
    };

    floatx4 acc[4][4] = {};
    const int rs = (quad ^ (lo & 3)) * 8;

    stage(0, 0);
    for (int k0 = 0; k0 < 1024; k0 += 32) {
        const int buf = (k0 >> 5) & 1;
        __syncthreads();
        if (k0 + 32 < 1024) stage(buf ^ 1, k0 + 32);

        bf16x8 a[4], b[4];
#pragma unroll
        for (int i = 0; i < 4; i++) a[i] = load8(&As[buf][wm * 64 + i * 16 + lo][rs]);
#pragma unroll
        for (int j = 0; j < 4; j++) b[j] = load8(&Bs[buf][wn * 64 + j * 16 + lo][rs]);
#pragma unroll
        for (int i = 0; i < 4; i++)
#pragma unroll
            for (int j = 0; j < 4; j++) acc[i][j] = MFMA(a[i], b[j], acc[i][j]);
    }

#pragma unroll
    for (int i = 0; i < 4; i++) {
#pragma unroll
        for (int j = 0; j < 4; j++) {
#pragma unroll
            for (int r = 0; r < 4; r++) {
                const int m = Ar0 + wm * 64 + i * 16 + quad * 4 + r;
                const int n = Br0 + wn * 64 + j * 16 + lo;
                const float v = acc[i][j][r] + bias[n];
                if (!TR) {
                    store_c(C + (size_t)m * 1024 + n, v);
                } else {
                    store_c(C + (size_t)(n >> 6) * (64 * 4096) + (size_t)(n & 63) * 4096 + m, v);
                }
            }
        }
    }
}

__global__ __launch_bounds__(256) void gemm_qkv(
    const bf16* __restrict__ qb, const bf16* __restrict__ kb, const bf16* __restrict__ vb,
    const bf16* __restrict__ Wq, const bf16* __restrict__ Wk, const bf16* __restrict__ Wv,
    const float* __restrict__ bq, const float* __restrict__ bk, const float* __restrict__ bv,
    bf16* __restrict__ Q, bf16* __restrict__ Kp, bf16* __restrict__ Vt) {
    if (blockIdx.z == 0)
        gemm_core<bf16>(qb, Wq, bq, Q, false);
    else if (blockIdx.z == 1)
        gemm_core<bf16>(kb, Wk, bk, Kp, false);
    else
        gemm_core<bf16>(vb, Wv, bv, Vt, true);  // Vt[h][d][s]
}

__global__ __launch_bounds__(256) void gemm_o(const bf16* __restrict__ O,
                                              const bf16* __restrict__ Wo,
                                              const float* __restrict__ bo,
                                              float* __restrict__ out) {
    gemm_core<float>(O, Wo, bo, out, false);
}

// ---------------- flash v11: v7 in-reg-P body + split-K(2) -----------------
// r5 theory: v10 proved 50KB/block packs only 2 blocks/CU (effective LDS
// pool < 150KB: 128KB pool or coarse granularity) -- occupancy stalled at
// 25% and the split-K overhead was paid for nothing. v7's in-reg-P body
// needs only 32KB (no Ps buffer): under EITHER pool hypothesis that packs
// 4 blocks/CU, and split-K(2)'s 1024-block grid supplies them -> 16
// waves/CU, 2x anything measured. Body is byte-identical to validated v7
// except loop bounds (kv0..kv0+2048) and the f32-partial epilogue
// (validated in v10: fixed-bias softmax => partials combine linearly).
__global__ __launch_bounds__(256) void flash_attn11(const bf16* __restrict__ Q,
                                                    const bf16* __restrict__ Kmat,
                                                    const bf16* __restrict__ Vt,
                                                    float* __restrict__ Pp,
                                                    float* __restrict__ lb) {
    __shared__ bf16 Ks[2][64][64];
    __shared__ bf16 Vs[2][64][64];

    const int tid = threadIdx.x;
    const int wv = tid >> 6;
    const int lane = tid & 63;
    const int quad = lane >> 4, lo = lane & 15;
    const int h = blockIdx.x;
    const int qb = blockIdx.y;
    const int z = blockIdx.z;
    const int kv0 = z * 2048;
    const int DM = 1024;
    const int q0 = qb * 128 + wv * 32;

    float* myP = Pp + (size_t)z * 4096 * 1024;
    float* myl = lb + z * 65536 + h * 4096;

    bf16x8 aQ[2][2];
#pragma unroll
    for (int qs = 0; qs < 2; qs++) {
        const bf16* qp = Q + (size_t)(q0 + qs * 16 + lo) * DM + h * 64 + quad * 8;
        aQ[qs][0] = load8(qp);
        aQ[qs][1] = load8(qp + 32);
    }

    bf16x8 bOnes;
#pragma unroll
    for (int i = 0; i < 8; i++) bOnes[i] = (bf16)1.0f;

    floatx4 Oacc[2][4] = {};
    floatx4 Lacc[2] = {};

    const int srow = lane >> 3, sseg = (lane & 7) ^ srow;
    const bf16* Kg = Kmat + (size_t)srow * DM + h * 64 + sseg * 8;
    const bf16* Vg = Vt + (size_t)h * 64 * 4096 + (size_t)srow * 4096 + sseg * 8;

    auto stage = [&](int buf, int kb2) {
#pragma unroll
        for (int c = 2 * wv; c < 2 * wv + 2; c++) {
            gload_lds(Kg + (size_t)(kb2 + c * 8) * DM, &Ks[buf][c * 8][0]);
            gload_lds(Vg + (size_t)(c * 8) * 4096 + kb2, &Vs[buf][c * 8][0]);
        }
    };

    const float C_SCALE = 0.18033688011112043f;  // 0.125 * log2(e)
    const float C_BIAS = 23.083120654223415f;    // 16 * log2(e)
    const int sw = lo & 7;
    const int vo = quad >> 1;        // V gather: logical-seg contribution
    const int vlo = (quad & 1) * 4;  // V gather: element offset in segment

    stage(0, kv0);
    for (int kb2 = kv0; kb2 < kv0 + 2048; kb2 += 64) {
        const int buf = (kb2 >> 6) & 1;
        __syncthreads();
        if (kb2 + 64 < kv0 + 2048) stage(buf ^ 1, kb2 + 64);

        // ---- S^T tile: rows=keys (t*16+quad*4+r), cols=q (lo) ----
        floatx4 st[2][4];
#pragma unroll
        for (int t = 0; t < 4; t++) {
            const bf16* krow = &Ks[buf][t * 16 + lo][0];
            const bf16x8 aK0 = load8(krow + ((quad ^ sw) * 8));
            const bf16x8 aK1 = load8(krow + (((quad + 4) ^ sw) * 8));
#pragma unroll
            for (int qs = 0; qs < 2; qs++) {
                floatx4 zz = {};
                zz = MFMA(aK0, aQ[qs][0], zz);
                st[qs][t] = MFMA(aK1, aQ[qs][1], zz);
            }
        }

        // ---- p = 2^(s*scale - bias), kept in registers ----
        bf16x4 pp[2][4];
#pragma unroll
        for (int qs = 0; qs < 2; qs++)
#pragma unroll
            for (int t = 0; t < 4; t++)
#pragma unroll
                for (int r = 0; r < 4; r++)
                    pp[qs][t][r] = (bf16)fast_exp2(fmaf(st[qs][t][r], C_SCALE, -C_BIAS));

        // ---- PV + l-accum straight from registers ----
#pragma unroll
        for (int kk = 0; kk < 2; kk++) {
            const bf16x8 aP0 = cat44(pp[0][2 * kk], pp[0][2 * kk + 1]);
            const bf16x8 aP1 = cat44(pp[1][2 * kk], pp[1][2 * kk + 1]);
            Lacc[0] = MFMA(aP0, bOnes, Lacc[0]);
            Lacc[1] = MFMA(aP1, bOnes, Lacc[1]);
#pragma unroll
            for (int nt = 0; nt < 4; nt++) {
                const bf16* vrow = &Vs[buf][nt * 16 + lo][0];
                const bf16x4 v0 = load4(vrow + (((kk * 4 + vo) ^ sw) << 3) + vlo);
                const bf16x4 v1 = load4(vrow + (((kk * 4 + 2 + vo) ^ sw) << 3) + vlo);
                const bf16x8 bV = cat44(v0, v1);
                Oacc[0][nt] = MFMA(aP0, bV, Oacc[0][nt]);
                Oacc[1][nt] = MFMA(aP1, bV, Oacc[1][nt]);
            }
        }
    }

    // ---- epilogue: write unnormalized f32 partial + l-partial ----
#pragma unroll
    for (int qs = 0; qs < 2; qs++)
#pragma unroll
        for (int r = 0; r < 4; r++) {
            const int row = q0 + qs * 16 + quad * 4 + r;
            if (lo == 0) myl[row] = Lacc[qs][r];
#pragma unroll
            for (int nt = 0; nt < 4; nt++) {
                myP[(size_t)row * DM + h * 64 + nt * 16 + lo] = Oacc[qs][nt][r];
            }
        }
}

// ---------------- combine: O = (P0+P1)/(l0+l1), f32 -> bf16 ----------------
__global__ __launch_bounds__(256) void combine_o(const float* __restrict__ P,
                                                 const float* __restrict__ lb,
                                                 bf16* __restrict__ Ob) {
    const size_t i = (size_t)(blockIdx.x * 256 + threadIdx.x) * 8;
    const int row = (int)(i >> 10), col = (int)(i & 1023), h = col >> 6;
    const float l = lb[h * 4096 + row] + lb[65536 + h * 4096 + row];
    const float inv = fast_rcp(l);
    const float4 a0 = *(const float4*)(P + i);
    const float4 a1 = *(const float4*)(P + i + 4);
    const float4 b0 = *(const float4*)(P + 4194304 + i);
    const float4 b1 = *(const float4*)(P + 4194304 + i + 4);
    bf16x8 r;
    r[0] = (bf16)((a0.x + b0.x) * inv);
    r[1] = (bf16)((a0.y + b0.y) * inv);
    r[2] = (bf16)((a0.z + b0.z) * inv);
    r[3] = (bf16)((a0.w + b0.w) * inv);
    r[4] = (bf16)((a1.x + b1.x) * inv);
    r[5] = (bf16)((a1.y + b1.y) * inv);
    r[6] = (bf16)((a1.z + b1.z) * inv);
    r[7] = (bf16)((a1.w + b1.w) * inv);
    *(bf16x8*)(Ob + i) = r;
}

extern "C" void kernel_launch(void* const* d_in, const int* in_sizes, int n_in,
                              void* d_out, int out_size, void* d_ws, size_t ws_size,
                              hipStream_t stream) {
    const float* query = (const float*)d_in[0];
    const float* key_i = (const float*)d_in[1];
    const float* value = (const float*)d_in[2];
    const float* Wq = (const float*)d_in[3];
    const float* bq = (const float*)d_in[4];
    const float* Wk = (const float*)d_in[5];
    const float* bk = (const float*)d_in[6];
    const float* Wv = (const float*)d_in[7];
    const float* bv = (const float*)d_in[8];
    const float* Wo = (const float*)d_in[9];
    const float* bo = (const float*)d_in[10];

    bf16* ws = (bf16*)d_ws;
    const size_t SZ = (size_t)4096 * 1024;  // 4M elems (8MB bf16)
    const size_t WZ = (size_t)1024 * 1024;  // 1M elems (2MB bf16)
    // 58.5MB layout. Phase 1 (cvt+gemm_qkv): qb..Wob live.
    // Phase 2 (flash): Q,K,Vt live; P0=[0,16MB) over qb+kb; P1=[16,32MB) over
    // vb+Wqb+Wkb+Wvb+pad (all dead). Phase 3: combine writes O into Q slot
    // (dead); gemm_o reads it. Wob lives at 56MB, l-partials at 58MB.
    bf16* qb = ws;                       // 8MB
    bf16* kb = ws + SZ;                  // 8MB
    bf16* vb = ws + 2 * SZ;              // 8MB
    bf16* Wqb = ws + 3 * SZ;             // 2MB
    bf16* Wkb = ws + 3 * SZ + WZ;        // 2MB
    bf16* Wvb = ws + 3 * SZ + 2 * WZ;    // 2MB
    // 2MB pad at ws + 3*SZ + 3*WZ (tail of P1)
    bf16* Q = ws + 3 * SZ + 4 * WZ;      // 8MB @32MB; O bf16 after flash
    bf16* K = Q + SZ;                    // 8MB @40MB
    bf16* Vt = Q + 2 * SZ;               // 8MB @48MB
    bf16* Wob = ws + 6 * SZ + 4 * WZ;    // 2MB @56MB
    float* lbuf = (float*)(ws + 6 * SZ + 5 * WZ);  // 512KB @58MB
    float* Pp = (float*)ws;              // P0 @0, P1 @16MB (contiguous f32)
    bf16* O = Q;                         // combine output aliases Q (dead)

    CvtArgs ca;
    const int SZi = 4096 * 1024, WZi = 1024 * 1024;
    ca.src[0] = query; ca.dst[0] = qb;  ca.n[0] = SZi;
    ca.src[1] = key_i; ca.dst[1] = kb;  ca.n[1] = SZi;
    ca.src[2] = value; ca.dst[2] = vb;  ca.n[2] = SZi;
    ca.src[3] = Wq;    ca.dst[3] = Wqb; ca.n[3] = WZi;
    ca.src[4] = Wk;    ca.dst[4] = Wkb; ca.n[4] = WZi;
    ca.src[5] = Wv;    ca.dst[5] = Wvb; ca.n[5] = WZi;
    ca.src[6] = Wo;    ca.dst[6] = Wob; ca.n[6] = WZi;
    cvt_bf16<<<dim3(2048, 7), 256, 0, stream>>>(ca);

    gemm_qkv<<<dim3(8, 32, 3), 256, 0, stream>>>(qb, kb, vb, Wqb, Wkb, Wvb,
                                                 bq, bk, bv, Q, K, Vt);
    flash_attn11<<<dim3(16, 32, 2), 256, 0, stream>>>(Q, K, Vt, Pp, lbuf);
    combine_o<<<2048, 256, 0, stream>>>(Pp, lbuf, O);
    gemm_o<<<dim3(8, 32), 256, 0, stream>>>(O, Wob, bo, (float*)d_out);
}

// Round 7
// 259.186 us; speedup vs baseline: 1.0784x; 1.0535x over previous
//
#include <hip/hip_runtime.h>

typedef __bf16 bf16;
typedef __bf16 bf16x8 __attribute__((ext_vector_type(8)));
typedef __bf16 bf16x4 __attribute__((ext_vector_type(4)));
typedef float floatx4 __attribute__((ext_vector_type(4)));

#define MFMA(a, b, c) __builtin_amdgcn_mfma_f32_16x16x32_bf16((a), (b), (c), 0, 0, 0)

__device__ inline bf16x8 load8(const bf16* p) { return *(const bf16x8*)(p); }
__device__ inline bf16x4 load4(const bf16* p) { return *(const bf16x4*)(p); }
__device__ inline bf16x8 cat44(bf16x4 a, bf16x4 b) {
    return __builtin_shufflevector(a, b, 0, 1, 2, 3, 4, 5, 6, 7);
}

__device__ inline void store_c(bf16* p, float v) { *p = (bf16)v; }
__device__ inline void store_c(float* p, float v) { *p = v; }

// Raw v_exp_f32. Safe: our exponent args are in [-40, 0], far from the f32
// denormal boundary (2^-126), so OCML's denormal-fixup path is dead code here.
__device__ inline float fast_exp2(float x) {
#if __has_builtin(__builtin_amdgcn_exp2f)
    return __builtin_amdgcn_exp2f(x);
#else
    float r;
    asm("v_exp_f32 %0, %1" : "=v"(r) : "v"(x));
    return r;
#endif
}

__device__ inline float fast_rcp(float x) {
#if __has_builtin(__builtin_amdgcn_rcpf)
    return __builtin_amdgcn_rcpf(x);
#else
    float r;
    asm("v_rcp_f32 %0, %1" : "=v"(r) : "v"(x));
    return r;
#endif
}

// Async global->LDS, 16B/lane; dest = wave-uniform base + lane*16.
__device__ inline void gload_lds(const bf16* g, bf16* l) {
    __builtin_amdgcn_global_load_lds(
        (const __attribute__((address_space(1))) void*)(g),
        (__attribute__((address_space(3))) void*)(l), 16, 0, 0);
}

// ---------------- fp32 -> bf16 bulk convert (7 tensors, one dispatch) ------
struct CvtArgs {
    const float* src[7];
    bf16* dst[7];
    int n[7];
};
__global__ __launch_bounds__(256) void cvt_bf16(CvtArgs a) {
    const int t = blockIdx.y;
    const int i = (blockIdx.x * 256 + threadIdx.x) * 8;
    if (i >= a.n[t]) return;
    const float4 u = *(const float4*)(a.src[t] + i);
    const float4 v = *(const float4*)(a.src[t] + i + 4);
    bf16x8 r;
    r[0] = (bf16)u.x; r[1] = (bf16)u.y; r[2] = (bf16)u.z; r[3] = (bf16)u.w;
    r[4] = (bf16)v.x; r[5] = (bf16)v.y; r[6] = (bf16)v.z; r[7] = (bf16)v.w;
    *(bf16x8*)(a.dst[t] + i) = r;
}

// ---------------- m97-style LDS GEMM (validated round 8) -------------------
template <typename TC>
__device__ inline void gemm_core(const bf16* __restrict__ A, const bf16* __restrict__ W,
                                 const float* __restrict__ bias, TC* __restrict__ C,
                                 bool TR) {
    __shared__ bf16 As[2][128][32];
    __shared__ bf16 Bs[2][128][32];

    const int tid = threadIdx.x;
    const int wv = tid >> 6, lane = tid & 63;
    const int quad = lane >> 4, lo = lane & 15;
    const int wm = wv >> 1, wn = wv & 1;
    const int Ar0 = blockIdx.y * 128, Br0 = blockIdx.x * 128;

    const int srow = lane >> 2, sseg = (lane & 3) ^ (srow & 3);
    const bf16* Ag = A + (size_t)(Ar0 + srow) * 1024 + sseg * 8;
    const bf16* Bg = W + (size_t)(Br0 + srow) * 1024 + sseg * 8;

    auto stage = [&](int buf, int k0) {
#pragma unroll
        for (int c = 2 * wv; c < 2 * wv + 2; c++) {
            gload_lds(Ag + (size_t)c * 16 * 1024 + k0, &As[buf][c * 16][0]);
            gload_lds(Bg + (size_t)c * 16 * 1024 + k0, &Bs[buf][c * 16][0]);
        }
    };

    floatx4 acc[4][4] = {};
    const int rs = (quad ^ (lo & 3)) * 8;

    stage(0, 0);
    for (int k0 = 0; k0 < 1024; k0 += 32) {
        const int buf = (k0 >> 5) & 1;
        __syncthreads();
        if (k0 + 32 < 1024) stage(buf ^ 1, k0 + 32);

        bf16x8 a[4], b[4];
#pragma unroll
        for (int i = 0; i < 4; i++) a[i] = load8(&As[buf][wm * 64 + i * 16 + lo][rs]);
#pragma unroll
        for (int j = 0; j < 4; j++) b[j] = load8(&Bs[buf][wn * 64 + j * 16 + lo][rs]);
#pragma unroll
        for (int i = 0; i < 4; i++)
#pragma unroll
            for (int j = 0; j < 4; j++) acc[i][j] = MFMA(a[i], b[j], acc[i][j]);
    }

#pragma unroll
    for (int i = 0; i < 4; i++) {
#pragma unroll
        for (int j = 0; j < 4; j++) {
#pragma unroll
            for (int r = 0; r < 4; r++) {
                const int m = Ar0 + wm * 64 + i * 16 + quad * 4 + r;
                const int n = Br0 + wn * 64 + j * 16 + lo;
                const float v = acc[i][j][r] + bias[n];
                if (!TR) {
                    store_c(C + (size_t)m * 1024 + n, v);
                } else {
                    store_c(C + (size_t)(n >> 6) * (64 * 4096) + (size_t)(n & 63) * 4096 + m, v);
                }
            }
        }
    }
}

__global__ __launch_bounds__(256) void gemm_qkv(
    const bf16* __restrict__ qb, const bf16* __restrict__ kb, const bf16* __restrict__ vb,
    const bf16* __restrict__ Wq, const bf16* __restrict__ Wk, const bf16* __restrict__ Wv,
    const float* __restrict__ bq, const float* __restrict__ bk, const float* __restrict__ bv,
    bf16* __restrict__ Q, bf16* __restrict__ Kp, bf16* __restrict__ Vt) {
    if (blockIdx.z == 0)
        gemm_core<bf16>(qb, Wq, bq, Q, false);
    else if (blockIdx.z == 1)
        gemm_core<bf16>(kb, Wk, bk, Kp, false);
    else
        gemm_core<bf16>(vb, Wv, bv, Vt, true);  // Vt[h][d][s]
}

__global__ __launch_bounds__(256) void gemm_o(const bf16* __restrict__ O,
                                              const bf16* __restrict__ Wo,
                                              const float* __restrict__ bo,
                                              float* __restrict__ out) {
    gemm_core<float>(O, Wo, bo, out, false);
}

// ---------------- flash v12: 8-wave/512t blocks + split-K(2) ---------------
// r6 theory: co-residency is empirically capped at 2 WORKGROUPS/CU in every
// config tried (256t x {32,40,50}KB, 512t x 32KB) -- waves/CU scale only
// with block size (v8's 512t hit 16 waves/CU). v8 also proved LDS has
// headroom at 16 waves/CU (it sustained 2x DS volume at v7's wall-clock).
// So: 8 waves x 32 q-rows (v8's de-amortization mistake avoided) = 256-row
// q-tile per block, split-K(2) for the 512-block grid, per-wave body
// byte-identical to v11. Staging: 1 K-chunk + 1 V-chunk per wave (8 waves
// cover the 64-row tile). 16 waves/CU with v11's per-wave instruction mix.
__global__ __launch_bounds__(512) void flash_attn12(const bf16* __restrict__ Q,
                                                    const bf16* __restrict__ Kmat,
                                                    const bf16* __restrict__ Vt,
                                                    float* __restrict__ Pp,
                                                    float* __restrict__ lb) {
    __shared__ bf16 Ks[2][64][64];
    __shared__ bf16 Vs[2][64][64];

    const int tid = threadIdx.x;
    const int wv = tid >> 6;  // 0..7
    const int lane = tid & 63;
    const int quad = lane >> 4, lo = lane & 15;
    const int h = blockIdx.x;
    const int qb = blockIdx.y;   // 0..15 (256-row q-tiles)
    const int z = blockIdx.z;
    const int kv0 = z * 2048;
    const int DM = 1024;
    const int q0 = qb * 256 + wv * 32;  // 32 q-rows per wave (v8 rule)

    float* myP = Pp + (size_t)z * 4096 * 1024;
    float* myl = lb + z * 65536 + h * 4096;

    bf16x8 aQ[2][2];
#pragma unroll
    for (int qs = 0; qs < 2; qs++) {
        const bf16* qp = Q + (size_t)(q0 + qs * 16 + lo) * DM + h * 64 + quad * 8;
        aQ[qs][0] = load8(qp);
        aQ[qs][1] = load8(qp + 32);
    }

    bf16x8 bOnes;
#pragma unroll
    for (int i = 0; i < 8; i++) bOnes[i] = (bf16)1.0f;

    floatx4 Oacc[2][4] = {};
    floatx4 Lacc[2] = {};

    const int srow = lane >> 3, sseg = (lane & 7) ^ srow;
    const bf16* Kg = Kmat + (size_t)srow * DM + h * 64 + sseg * 8;
    const bf16* Vg = Vt + (size_t)h * 64 * 4096 + (size_t)srow * 4096 + sseg * 8;

    // 8 waves cover the 64-row K/V tile: one 8-row chunk each.
    auto stage = [&](int buf, int kb2) {
        gload_lds(Kg + (size_t)(kb2 + wv * 8) * DM, &Ks[buf][wv * 8][0]);
        gload_lds(Vg + (size_t)(wv * 8) * 4096 + kb2, &Vs[buf][wv * 8][0]);
    };

    const float C_SCALE = 0.18033688011112043f;  // 0.125 * log2(e)
    const float C_BIAS = 23.083120654223415f;    // 16 * log2(e)
    const int sw = lo & 7;
    const int vo = quad >> 1;        // V gather: logical-seg contribution
    const int vlo = (quad & 1) * 4;  // V gather: element offset in segment

    stage(0, kv0);
    for (int kb2 = kv0; kb2 < kv0 + 2048; kb2 += 64) {
        const int buf = (kb2 >> 6) & 1;
        __syncthreads();
        if (kb2 + 64 < kv0 + 2048) stage(buf ^ 1, kb2 + 64);

        // ---- S^T tile: rows=keys (t*16+quad*4+r), cols=q (lo) ----
        floatx4 st[2][4];
#pragma unroll
        for (int t = 0; t < 4; t++) {
            const bf16* krow = &Ks[buf][t * 16 + lo][0];
            const bf16x8 aK0 = load8(krow + ((quad ^ sw) * 8));
            const bf16x8 aK1 = load8(krow + (((quad + 4) ^ sw) * 8));
#pragma unroll
            for (int qs = 0; qs < 2; qs++) {
                floatx4 zz = {};
                zz = MFMA(aK0, aQ[qs][0], zz);
                st[qs][t] = MFMA(aK1, aQ[qs][1], zz);
            }
        }

        // ---- p = 2^(s*scale - bias), kept in registers ----
        bf16x4 pp[2][4];
#pragma unroll
        for (int qs = 0; qs < 2; qs++)
#pragma unroll
            for (int t = 0; t < 4; t++)
#pragma unroll
                for (int r = 0; r < 4; r++)
                    pp[qs][t][r] = (bf16)fast_exp2(fmaf(st[qs][t][r], C_SCALE, -C_BIAS));

        // ---- PV + l-accum straight from registers ----
#pragma unroll
        for (int kk = 0; kk < 2; kk++) {
            const bf16x8 aP0 = cat44(pp[0][2 * kk], pp[0][2 * kk + 1]);
            const bf16x8 aP1 = cat44(pp[1][2 * kk], pp[1][2 * kk + 1]);
            Lacc[0] = MFMA(aP0, bOnes, Lacc[0]);
            Lacc[1] = MFMA(aP1, bOnes, Lacc[1]);
#pragma unroll
            for (int nt = 0; nt < 4; nt++) {
                const bf16* vrow = &Vs[buf][nt * 16 + lo][0];
                const bf16x4 v0 = load4(vrow + (((kk * 4 + vo) ^ sw) << 3) + vlo);
                const bf16x4 v1 = load4(vrow + (((kk * 4 + 2 + vo) ^ sw) << 3) + vlo);
                const bf16x8 bV = cat44(v0, v1);
                Oacc[0][nt] = MFMA(aP0, bV, Oacc[0][nt]);
                Oacc[1][nt] = MFMA(aP1, bV, Oacc[1][nt]);
            }
        }
    }

    // ---- epilogue: write unnormalized f32 partial + l-partial ----
#pragma unroll
    for (int qs = 0; qs < 2; qs++)
#pragma unroll
        for (int r = 0; r < 4; r++) {
            const int row = q0 + qs * 16 + quad * 4 + r;
            if (lo == 0) myl[row] = Lacc[qs][r];
#pragma unroll
            for (int nt = 0; nt < 4; nt++) {
                myP[(size_t)row * DM + h * 64 + nt * 16 + lo] = Oacc[qs][nt][r];
            }
        }
}

// ---------------- combine: O = (P0+P1)/(l0+l1), f32 -> bf16 ----------------
__global__ __launch_bounds__(256) void combine_o(const float* __restrict__ P,
                                                 const float* __restrict__ lb,
                                                 bf16* __restrict__ Ob) {
    const size_t i = (size_t)(blockIdx.x * 256 + threadIdx.x) * 8;
    const int row = (int)(i >> 10), col = (int)(i & 1023), h = col >> 6;
    const float l = lb[h * 4096 + row] + lb[65536 + h * 4096 + row];
    const float inv = fast_rcp(l);
    const float4 a0 = *(const float4*)(P + i);
    const float4 a1 = *(const float4*)(P + i + 4);
    const float4 b0 = *(const float4*)(P + 4194304 + i);
    const float4 b1 = *(const float4*)(P + 4194304 + i + 4);
    bf16x8 r;
    r[0] = (bf16)((a0.x + b0.x) * inv);
    r[1] = (bf16)((a0.y + b0.y) * inv);
    r[2] = (bf16)((a0.z + b0.z) * inv);
    r[3] = (bf16)((a0.w + b0.w) * inv);
    r[4] = (bf16)((a1.x + b1.x) * inv);
    r[5] = (bf16)((a1.y + b1.y) * inv);
    r[6] = (bf16)((a1.z + b1.z) * inv);
    r[7] = (bf16)((a1.w + b1.w) * inv);
    *(bf16x8*)(Ob + i) = r;
}

extern "C" void kernel_launch(void* const* d_in, const int* in_sizes, int n_in,
                              void* d_out, int out_size, void* d_ws, size_t ws_size,
                              hipStream_t stream) {
    const float* query = (const float*)d_in[0];
    const float* key_i = (const float*)d_in[1];
    const float* value = (const float*)d_in[2];
    const float* Wq = (const float*)d_in[3];
    const float* bq = (const float*)d_in[4];
    const float* Wk = (const float*)d_in[5];
    const float* bk = (const float*)d_in[6];
    const float* Wv = (const float*)d_in[7];
    const float* bv = (const float*)d_in[8];
    const float* Wo = (const float*)d_in[9];
    const float* bo = (const float*)d_in[10];

    bf16* ws = (bf16*)d_ws;
    const size_t SZ = (size_t)4096 * 1024;  // 4M elems (8MB bf16)
    const size_t WZ = (size_t)1024 * 1024;  // 1M elems (2MB bf16)
    // 58.5MB layout. Phase 1 (cvt+gemm_qkv): qb..Wob live.
    // Phase 2 (flash): Q,K,Vt live; P0=[0,16MB) over qb+kb; P1=[16,32MB) over
    // vb+Wqb+Wkb+Wvb+pad (all dead). Phase 3: combine writes O into Q slot
    // (dead); gemm_o reads it. Wob lives at 56MB, l-partials at 58MB.
    bf16* qb = ws;                       // 8MB
    bf16* kb = ws + SZ;                  // 8MB
    bf16* vb = ws + 2 * SZ;              // 8MB
    bf16* Wqb = ws + 3 * SZ;             // 2MB
    bf16* Wkb = ws + 3 * SZ + WZ;        // 2MB
    bf16* Wvb = ws + 3 * SZ + 2 * WZ;    // 2MB
    // 2MB pad at ws + 3*SZ + 3*WZ (tail of P1)
    bf16* Q = ws + 3 * SZ + 4 * WZ;      // 8MB @32MB; O bf16 after flash
    bf16* K = Q + SZ;                    // 8MB @40MB
    bf16* Vt = Q + 2 * SZ;               // 8MB @48MB
    bf16* Wob = ws + 6 * SZ + 4 * WZ;    // 2MB @56MB
    float* lbuf = (float*)(ws + 6 * SZ + 5 * WZ);  // 512KB @58MB
    float* Pp = (float*)ws;              // P0 @0, P1 @16MB (contiguous f32)
    bf16* O = Q;                         // combine output aliases Q (dead)

    CvtArgs ca;
    const int SZi = 4096 * 1024, WZi = 1024 * 1024;
    ca.src[0] = query; ca.dst[0] = qb;  ca.n[0] = SZi;
    ca.src[1] = key_i; ca.dst[1] = kb;  ca.n[1] = SZi;
    ca.src[2] = value; ca.dst[2] = vb;  ca.n[2] = SZi;
    ca.src[3] = Wq;    ca.dst[3] = Wqb; ca.n[3] = WZi;
    ca.src[4] = Wk;    ca.dst[4] = Wkb; ca.n[4] = WZi;
    ca.src[5] = Wv;    ca.dst[5] = Wvb; ca.n[5] = WZi;
    ca.src[6] = Wo;    ca.dst[6] = Wob; ca.n[6] = WZi;
    cvt_bf16<<<dim3(2048, 7), 256, 0, stream>>>(ca);

    gemm_qkv<<<dim3(8, 32, 3), 256, 0, stream>>>(qb, kb, vb, Wqb, Wkb, Wvb,
                                                 bq, bk, bv, Q, K, Vt);
    flash_attn12<<<dim3(16, 16, 2), 512, 0, stream>>>(Q, K, Vt, Pp, lbuf);
    combine_o<<<2048, 256, 0, stream>>>(Pp, lbuf, O);
    gemm_o<<<dim3(8, 32), 256, 0, stream>>>(O, Wob, bo, (float*)d_out);
}